// Round 2
// baseline (990.351 us; speedup 1.0000x reference)
//
#include <hip/hip_runtime.h>

#define N_NODES 50000
#define N_EDGES 800000
#define D_IN    128
#define D_E     64
#define NH      4
#define F_TOT   128          // NH * D_OUT
#define NEG_SLOPE 0.2f

typedef __attribute__((ext_vector_type(8))) short short8;   // 8 bf16
typedef __attribute__((ext_vector_type(4))) float f32x4;

__device__ __forceinline__ short f2bf(float x) {            // RNE f32->bf16
    unsigned u = __float_as_uint(x);
    u += 0x7FFFu + ((u >> 16) & 1u);
    return (short)(u >> 16);
}

// ---------------------------------------------------------------------------
// K1: HT[n][f] = sum_k H[n][k] * W[f][k]   (fp32, -> workspace)
// ---------------------------------------------------------------------------
__global__ __launch_bounds__(256) void k_node_transform(
    const float* __restrict__ H, const float* __restrict__ W,
    float* __restrict__ HT)
{
    __shared__ float wt[D_IN * F_TOT];   // wt[k*128+f] = W[f][k]
    const int tid = threadIdx.x;
    for (int i = tid; i < D_IN * F_TOT; i += 256) {
        const int f = i & 127, k = i >> 7;
        wt[k * F_TOT + f] = W[f * D_IN + k];
    }
    __syncthreads();

    const int l = tid & 63;
    const int w = tid >> 6;
    const int gwave  = blockIdx.x * 4 + w;
    const int nwaves = gridDim.x * 4;
    const int ngroups = N_NODES / 8;     // 6250, exact

    for (int grp = gwave; grp < ngroups; grp += nwaves) {
        const int g = grp * 8;
        float ax[8], ay[8];
#pragma unroll
        for (int j = 0; j < 8; ++j) { ax[j] = 0.f; ay[j] = 0.f; }

        for (int k4 = 0; k4 < D_IN / 4; ++k4) {
            float hv[8][4];
#pragma unroll
            for (int j = 0; j < 8; ++j)
                *(float4*)hv[j] = *(const float4*)&H[(size_t)(g + j) * D_IN + k4 * 4];
#pragma unroll
            for (int kk = 0; kk < 4; ++kk) {
                const float2 wk = *(const float2*)&wt[(k4 * 4 + kk) * F_TOT + 2 * l];
#pragma unroll
                for (int j = 0; j < 8; ++j) {
                    ax[j] = fmaf(wk.x, hv[j][kk], ax[j]);
                    ay[j] = fmaf(wk.y, hv[j][kk], ay[j]);
                }
            }
        }
#pragma unroll
        for (int j = 0; j < 8; ++j) {
            float2 r; r.x = ax[j]; r.y = ay[j];
            *(float2*)&HT[(size_t)(g + j) * F_TOT + 2 * l] = r;
        }
    }
}

// ---------------------------------------------------------------------------
// K2a: histogram of dst degrees
// ---------------------------------------------------------------------------
__global__ __launch_bounds__(256) void k_hist(
    const int* __restrict__ EI, int* __restrict__ deg)
{
    const int e = blockIdx.x * 256 + threadIdx.x;
    if (e < N_EDGES) atomicAdd(&deg[EI[N_EDGES + e]], 1);
}

// ---------------------------------------------------------------------------
// K2b: single-block exclusive scan of deg -> row_start[0..N], cursor copy
// ---------------------------------------------------------------------------
__global__ __launch_bounds__(1024) void k_scan(
    const int* __restrict__ deg, int* __restrict__ row_start,
    int* __restrict__ cursor)
{
    __shared__ int wsum[16];
    __shared__ int carry;
    const int tid = threadIdx.x;
    const int l = tid & 63;
    const int wv = tid >> 6;
    if (tid == 0) carry = 0;

    for (int base = 0; base < N_NODES; base += 1024) {
        __syncthreads();                       // [A] carry ready, wsum free
        const int cb = carry;
        const int i = base + tid;
        const int v = (i < N_NODES) ? deg[i] : 0;
        int x = v;                             // inclusive wave scan
#pragma unroll
        for (int off = 1; off < 64; off <<= 1) {
            int t = __shfl_up(x, off, 64);
            if (l >= off) x += t;
        }
        if (l == 63) wsum[wv] = x;
        __syncthreads();                       // [B] wsum ready
        int wave_off = 0;
        for (int k = 0; k < wv; ++k) wave_off += wsum[k];
        int tot = 0;
#pragma unroll
        for (int k = 0; k < 16; ++k) tot += wsum[k];
        const int excl = cb + wave_off + (x - v);
        if (i < N_NODES) { row_start[i] = excl; cursor[i] = excl; }
        __syncthreads();                       // [C] all read cb/wsum
        if (tid == 0) carry = cb + tot;
    }
    __syncthreads();
    if (tid == 0) row_start[N_NODES] = carry;
}

// ---------------------------------------------------------------------------
// K2c: CSR permutation build. perm[pos] = {eid, src}, pos from cursor atomic.
// ---------------------------------------------------------------------------
__global__ __launch_bounds__(256) void k_permute(
    const int* __restrict__ EI, int* __restrict__ cursor,
    int2* __restrict__ perm)
{
    const int e = blockIdx.x * 256 + threadIdx.x;
    if (e < N_EDGES) {
        const int src = EI[e];
        const int dst = EI[N_EDGES + e];
        const int pos = atomicAdd(&cursor[dst], 1);
        perm[pos] = make_int2(e, src);
    }
}

// ---------------------------------------------------------------------------
// K3: FUSED logits + aggregation. One wave per dst node.
//   Per 16-edge CSR tile (lane-per-edge layout, operand-swapped MFMA):
//     D(16f x 16e) = We_tile(16f x 32k) @ E_tile^T(32k x 16e)
//     D: col=lane&15 -> EDGE (CSR slot), row=(lane>>4)*4+reg -> feature
//   Fusion wins vs the split pipeline:
//     - HT[dst] loaded ONCE per node (was a per-edge gather: -410MB)
//     - HT[src] gathered once, reused from regs for logit AND message
//       (kills k_aggregate's entire re-gather: -410MB)
//     - no wperm/srcperm materialize+reload, no in-loop cursor atomic
//   Softmax denom sw and weighted sums am[] accumulate per-lane (per-edge);
//   one 4-step xor-reduce over the 16 edge-lanes at node end, then the 4
//   r16==0 lanes (one per g4 feature group) store their 32 features.
// ---------------------------------------------------------------------------
__global__ __launch_bounds__(256, 3) void k_fused(
    const float* __restrict__ E, const float* __restrict__ We,
    const float* __restrict__ att, const float* __restrict__ HT,
    const int2* __restrict__ perm, const int* __restrict__ row_start,
    float* __restrict__ out)
{
    __shared__ short8 s_bf[8][2][64];   // 16 KB: per-lane We fragments (bf16)
    __shared__ f32x4  s_att[8][4];      // 512 B

    const int tid = threadIdx.x;
    const int l   = tid & 63;
    const int wv  = tid >> 6;
    const int r16 = l & 15;          // edge slot within tile
    const int g4  = l >> 4;          // feature group / k-chunk selector

    if (wv == 0) {
#pragma unroll
        for (int ft = 0; ft < 8; ++ft) {
#pragma unroll
            for (int kc = 0; kc < 2; ++kc) {
                const float* wp = &We[(size_t)(ft * 16 + r16) * D_E + kc * 32 + g4 * 8];
                const f32x4 lo = *(const f32x4*)wp;
                const f32x4 hi = *(const f32x4*)(wp + 4);
                short8 b;
                b[0] = f2bf(lo[0]); b[1] = f2bf(lo[1]); b[2] = f2bf(lo[2]); b[3] = f2bf(lo[3]);
                b[4] = f2bf(hi[0]); b[5] = f2bf(hi[1]); b[6] = f2bf(hi[2]); b[7] = f2bf(hi[3]);
                s_bf[ft][kc][l] = b;
            }
        }
        if (l < 32) {
            const int ft = l >> 2, g = l & 3;
            s_att[ft][g] = *(const f32x4*)&att[ft * 16 + g * 4];
        }
    }
    __syncthreads();

    const int n = blockIdx.x * 4 + wv;
    if (n >= N_NODES) return;
    const int beg = row_start[n];
    const int end = row_start[n + 1];

    // this node's own HT row (dst term), fragment layout, loaded once
    f32x4 hd4[8];
#pragma unroll
    for (int ft = 0; ft < 8; ++ft)
        hd4[ft] = *(const f32x4*)&HT[(size_t)n * F_TOT + ft * 16 + g4 * 4];

    f32x4 am[8];                        // per-lane message accum (this edge)
#pragma unroll
    for (int ft = 0; ft < 8; ++ft) am[ft] = (f32x4){0.f, 0.f, 0.f, 0.f};
    float sw[4] = {0.f, 0.f, 0.f, 0.f}; // per-lane softmax denom partials

    for (int t = beg; t < end; t += 16) {
        const int  idx   = t + r16;
        const bool valid = idx < end;
        const int2 pe    = perm[valid ? idx : end - 1];
        const int  eid   = pe.x;
        const int  sr    = pe.y;

        // HT[src] gather: 8 independent dwordx4 (reused for logit AND message)
        const float* hsp = &HT[(size_t)sr * F_TOT + g4 * 4];
        f32x4 hs4[8];
#pragma unroll
        for (int ft = 0; ft < 8; ++ft)
            hs4[ft] = *(const f32x4*)(hsp + ft * 16);

        // E row -> bf16 B-fragments
        short8 af[2];
#pragma unroll
        for (int kc = 0; kc < 2; ++kc) {
            const float* ep = &E[(size_t)eid * D_E + kc * 32 + g4 * 8];
            const f32x4 lo = *(const f32x4*)ep;
            const f32x4 hi = *(const f32x4*)(ep + 4);
            short8 a;
            a[0] = f2bf(lo[0]); a[1] = f2bf(lo[1]); a[2] = f2bf(lo[2]); a[3] = f2bf(lo[3]);
            a[4] = f2bf(hi[0]); a[5] = f2bf(hi[1]); a[6] = f2bf(hi[2]); a[7] = f2bf(hi[3]);
            af[kc] = a;
        }

        float ph[4] = {0.f, 0.f, 0.f, 0.f};
#pragma unroll
        for (int ft = 0; ft < 8; ++ft) {
            f32x4 z = {0.f, 0.f, 0.f, 0.f};
            z = __builtin_amdgcn_mfma_f32_16x16x32_bf16(s_bf[ft][0][l], af[0], z, 0, 0, 0);
            const f32x4 acc =
                __builtin_amdgcn_mfma_f32_16x16x32_bf16(s_bf[ft][1][l], af[1], z, 0, 0, 0);
            const f32x4 at = s_att[ft][g4];
#pragma unroll
            for (int r = 0; r < 4; ++r) {
                float v = hs4[ft][r] + hd4[ft][r] + acc[r];
                v = v > 0.f ? v : NEG_SLOPE * v;
                ph[ft >> 1] = fmaf(v, at[r], ph[ft >> 1]);
            }
        }
        // reduce over the 4 g4-lanes sharing this edge (lanes l^16, l^32)
#pragma unroll
        for (int h = 0; h < 4; ++h) {
            ph[h] += __shfl_xor(ph[h], 16, 64);
            ph[h] += __shfl_xor(ph[h], 32, 64);
        }
        float w[4];
#pragma unroll
        for (int h = 0; h < 4; ++h) {
            w[h] = valid ? __expf(ph[h]) : 0.f;
            sw[h] += w[h];
        }
        // message accumulation: reuse hs4 registers (no second gather!)
#pragma unroll
        for (int ft = 0; ft < 8; ++ft) {
            const float wh = w[ft >> 1];
#pragma unroll
            for (int r = 0; r < 4; ++r)
                am[ft][r] = fmaf(wh, hs4[ft][r], am[ft][r]);
        }
    }

    // reduce over the 16 edge-lanes (masks 1..8 stay inside the g4 group)
#pragma unroll
    for (int m = 1; m < 16; m <<= 1) {
#pragma unroll
        for (int h = 0; h < 4; ++h) sw[h] += __shfl_xor(sw[h], m, 64);
#pragma unroll
        for (int ft = 0; ft < 8; ++ft)
#pragma unroll
            for (int r = 0; r < 4; ++r)
                am[ft][r] += __shfl_xor(am[ft][r], m, 64);
    }
    float inv[4];
#pragma unroll
    for (int h = 0; h < 4; ++h) inv[h] = 1.f / (sw[h] + 1e-16f);

    if (r16 == 0) {                     // 4 lanes store 32 features each
#pragma unroll
        for (int ft = 0; ft < 8; ++ft) {
            f32x4 o;
#pragma unroll
            for (int r = 0; r < 4; ++r) o[r] = am[ft][r] * inv[ft >> 1];
            *(f32x4*)&out[(size_t)n * F_TOT + ft * 16 + g4 * 4] = o;
        }
    }
}

extern "C" void kernel_launch(void* const* d_in, const int* in_sizes, int n_in,
                              void* d_out, int out_size, void* d_ws, size_t ws_size,
                              hipStream_t stream)
{
    const float* H   = (const float*)d_in[0];
    const int*   EI  = (const int*)d_in[1];
    const float* E   = (const float*)d_in[2];
    const float* W   = (const float*)d_in[3];
    const float* We  = (const float*)d_in[4];
    const float* att = (const float*)d_in[5];
    float* out = (float*)d_out;

    // workspace layout (~33 MB)
    float* HT        = (float*)d_ws;                          // 6.4M f32
    int2*  perm      = (int2*)(HT + (size_t)N_NODES * F_TOT); // 800k int2
    int*   deg       = (int*)(perm + N_EDGES);                // 50k
    int*   row_start = deg + N_NODES;                         // 50k+1
    int*   cursor    = row_start + N_NODES + 1;               // 50k

    hipMemsetAsync(deg, 0, N_NODES * sizeof(int), stream);

    k_hist<<<(N_EDGES + 255) / 256, 256, 0, stream>>>(EI, deg);
    k_scan<<<1, 1024, 0, stream>>>(deg, row_start, cursor);
    k_node_transform<<<512, 256, 0, stream>>>(H, W, HT);
    k_permute<<<(N_EDGES + 255) / 256, 256, 0, stream>>>(EI, cursor, perm);
    k_fused<<<(N_NODES + 3) / 4, 256, 0, stream>>>(E, We, att, HT,
                                                   perm, row_start, out);
}

// Round 3
// 731.978 us; speedup vs baseline: 1.3530x; 1.3530x over previous
//
#include <hip/hip_runtime.h>

#define N_NODES 50000
#define N_EDGES 800000
#define D_IN    128
#define D_E     64
#define NH      4
#define F_TOT   128          // NH * D_OUT
#define NEG_SLOPE 0.2f

typedef __attribute__((ext_vector_type(8))) short short8;   // 8 bf16
typedef __attribute__((ext_vector_type(4))) float f32x4;

__device__ __forceinline__ short f2bf(float x) {            // RNE f32->bf16
    unsigned u = __float_as_uint(x);
    u += 0x7FFFu + ((u >> 16) & 1u);
    return (short)(u >> 16);
}

// ---------------------------------------------------------------------------
// K1: HT[n][f] = sum_k H[n][k] * W[f][k]   (fp32, -> workspace)
// ---------------------------------------------------------------------------
__global__ __launch_bounds__(256) void k_node_transform(
    const float* __restrict__ H, const float* __restrict__ W,
    float* __restrict__ HT)
{
    __shared__ float wt[D_IN * F_TOT];   // wt[k*128+f] = W[f][k]
    const int tid = threadIdx.x;
    for (int i = tid; i < D_IN * F_TOT; i += 256) {
        const int f = i & 127, k = i >> 7;
        wt[k * F_TOT + f] = W[f * D_IN + k];
    }
    __syncthreads();

    const int l = tid & 63;
    const int w = tid >> 6;
    const int gwave  = blockIdx.x * 4 + w;
    const int nwaves = gridDim.x * 4;
    const int ngroups = N_NODES / 8;     // 6250, exact

    for (int grp = gwave; grp < ngroups; grp += nwaves) {
        const int g = grp * 8;
        float ax[8], ay[8];
#pragma unroll
        for (int j = 0; j < 8; ++j) { ax[j] = 0.f; ay[j] = 0.f; }

        for (int k4 = 0; k4 < D_IN / 4; ++k4) {
            float hv[8][4];
#pragma unroll
            for (int j = 0; j < 8; ++j)
                *(float4*)hv[j] = *(const float4*)&H[(size_t)(g + j) * D_IN + k4 * 4];
#pragma unroll
            for (int kk = 0; kk < 4; ++kk) {
                const float2 wk = *(const float2*)&wt[(k4 * 4 + kk) * F_TOT + 2 * l];
#pragma unroll
                for (int j = 0; j < 8; ++j) {
                    ax[j] = fmaf(wk.x, hv[j][kk], ax[j]);
                    ay[j] = fmaf(wk.y, hv[j][kk], ay[j]);
                }
            }
        }
#pragma unroll
        for (int j = 0; j < 8; ++j) {
            float2 r; r.x = ax[j]; r.y = ay[j];
            *(float2*)&HT[(size_t)(g + j) * F_TOT + 2 * l] = r;
        }
    }
}

// ---------------------------------------------------------------------------
// K2a: histogram of dst degrees
// ---------------------------------------------------------------------------
__global__ __launch_bounds__(256) void k_hist(
    const int* __restrict__ EI, int* __restrict__ deg)
{
    const int e = blockIdx.x * 256 + threadIdx.x;
    if (e < N_EDGES) atomicAdd(&deg[EI[N_EDGES + e]], 1);
}

// ---------------------------------------------------------------------------
// K2b: single-block exclusive scan of deg -> row_start[0..N], cursor copy
// ---------------------------------------------------------------------------
__global__ __launch_bounds__(1024) void k_scan(
    const int* __restrict__ deg, int* __restrict__ row_start,
    int* __restrict__ cursor)
{
    __shared__ int wsum[16];
    __shared__ int carry;
    const int tid = threadIdx.x;
    const int l = tid & 63;
    const int wv = tid >> 6;
    if (tid == 0) carry = 0;

    for (int base = 0; base < N_NODES; base += 1024) {
        __syncthreads();                       // [A] carry ready, wsum free
        const int cb = carry;
        const int i = base + tid;
        const int v = (i < N_NODES) ? deg[i] : 0;
        int x = v;                             // inclusive wave scan
#pragma unroll
        for (int off = 1; off < 64; off <<= 1) {
            int t = __shfl_up(x, off, 64);
            if (l >= off) x += t;
        }
        if (l == 63) wsum[wv] = x;
        __syncthreads();                       // [B] wsum ready
        int wave_off = 0;
        for (int k = 0; k < wv; ++k) wave_off += wsum[k];
        int tot = 0;
#pragma unroll
        for (int k = 0; k < 16; ++k) tot += wsum[k];
        const int excl = cb + wave_off + (x - v);
        if (i < N_NODES) { row_start[i] = excl; cursor[i] = excl; }
        __syncthreads();                       // [C] all read cb/wsum
        if (tid == 0) carry = cb + tot;
    }
    __syncthreads();
    if (tid == 0) row_start[N_NODES] = carry;
}

// ---------------------------------------------------------------------------
// K2c: CSR permutation build. perm[pos] = {eid, src}, pos from cursor atomic.
// ---------------------------------------------------------------------------
__global__ __launch_bounds__(256) void k_permute(
    const int* __restrict__ EI, int* __restrict__ cursor,
    int2* __restrict__ perm)
{
    const int e = blockIdx.x * 256 + threadIdx.x;
    if (e < N_EDGES) {
        const int src = EI[e];
        const int dst = EI[N_EDGES + e];
        const int pos = atomicAdd(&cursor[dst], 1);
        perm[pos] = make_int2(e, src);
    }
}

// ---------------------------------------------------------------------------
// K3: FUSED logits + aggregation. One wave per dst node.
//   R3 fix vs R2: the 544us regression was SCRATCH SPILL (WRITE_SIZE 875MB on
//   a kernel that stores 25.6MB). Register surgery, no algorithm change:
//     - hd4 (per-node constant) moved to LDS s_hd[8][4][64] (-32 VGPRs)
//     - __launch_bounds__(256,2): the (256,3) bound empirically capped the
//       allocator at 84 VGPRs, forcing am[] to scratch. Live set now ~100.
//   Per 16-edge CSR tile (lane-per-edge layout, operand-swapped MFMA):
//     D(16f x 16e) = We_tile(16f x 32k) @ E_tile^T(32k x 16e)
//     D: col=lane&15 -> EDGE (CSR slot), row=(lane>>4)*4+reg -> feature
// ---------------------------------------------------------------------------
__global__ __launch_bounds__(256, 2) void k_fused(
    const float* __restrict__ E, const float* __restrict__ We,
    const float* __restrict__ att, const float* __restrict__ HT,
    const int2* __restrict__ perm, const int* __restrict__ row_start,
    float* __restrict__ out)
{
    __shared__ short8 s_bf[8][2][64];   // 16 KB: per-lane We fragments (bf16)
    __shared__ f32x4  s_att[8][4];      // 512 B
    __shared__ f32x4  s_hd[8][4][64];   // 32 KB: per-wave dst-row fragments

    const int tid = threadIdx.x;
    const int l   = tid & 63;
    const int wv  = tid >> 6;
    const int r16 = l & 15;          // edge slot within tile
    const int g4  = l >> 4;          // feature group / k-chunk selector

    if (wv == 0) {
#pragma unroll
        for (int ft = 0; ft < 8; ++ft) {
#pragma unroll
            for (int kc = 0; kc < 2; ++kc) {
                const float* wp = &We[(size_t)(ft * 16 + r16) * D_E + kc * 32 + g4 * 8];
                const f32x4 lo = *(const f32x4*)wp;
                const f32x4 hi = *(const f32x4*)(wp + 4);
                short8 b;
                b[0] = f2bf(lo[0]); b[1] = f2bf(lo[1]); b[2] = f2bf(lo[2]); b[3] = f2bf(lo[3]);
                b[4] = f2bf(hi[0]); b[5] = f2bf(hi[1]); b[6] = f2bf(hi[2]); b[7] = f2bf(hi[3]);
                s_bf[ft][kc][l] = b;
            }
        }
        if (l < 32) {
            const int ft = l >> 2, g = l & 3;
            s_att[ft][g] = *(const f32x4*)&att[ft * 16 + g * 4];
        }
    }
    __syncthreads();

    const int n = blockIdx.x * 4 + wv;
    if (n >= N_NODES) return;
    const int beg = row_start[n];
    const int end = row_start[n + 1];

    // this node's own HT row (dst term) -> LDS, written once per node
    {
        const float* hrow = &HT[(size_t)n * F_TOT + g4 * 4];
#pragma unroll
        for (int ft = 0; ft < 8; ++ft)
            s_hd[ft][wv][l] = *(const f32x4*)(hrow + ft * 16);
    }

    f32x4 am[8];                        // per-lane message accum (this edge)
#pragma unroll
    for (int ft = 0; ft < 8; ++ft) am[ft] = (f32x4){0.f, 0.f, 0.f, 0.f};
    float sw[4] = {0.f, 0.f, 0.f, 0.f}; // per-lane softmax denom partials

    for (int t = beg; t < end; t += 16) {
        const int  idx   = t + r16;
        const bool valid = idx < end;
        const int2 pe    = perm[valid ? idx : end - 1];
        const int  eid   = pe.x;
        const int  sr    = pe.y;

        // HT[src] gather: 8 independent dwordx4 (reused for logit AND message)
        const float* hsp = &HT[(size_t)sr * F_TOT + g4 * 4];
        f32x4 hs4[8];
#pragma unroll
        for (int ft = 0; ft < 8; ++ft)
            hs4[ft] = *(const f32x4*)(hsp + ft * 16);

        // E row -> bf16 B-fragments
        short8 af[2];
#pragma unroll
        for (int kc = 0; kc < 2; ++kc) {
            const float* ep = &E[(size_t)eid * D_E + kc * 32 + g4 * 8];
            const f32x4 lo = *(const f32x4*)ep;
            const f32x4 hi = *(const f32x4*)(ep + 4);
            short8 a;
            a[0] = f2bf(lo[0]); a[1] = f2bf(lo[1]); a[2] = f2bf(lo[2]); a[3] = f2bf(lo[3]);
            a[4] = f2bf(hi[0]); a[5] = f2bf(hi[1]); a[6] = f2bf(hi[2]); a[7] = f2bf(hi[3]);
            af[kc] = a;
        }

        float ph[4] = {0.f, 0.f, 0.f, 0.f};
#pragma unroll
        for (int ft = 0; ft < 8; ++ft) {
            f32x4 z = {0.f, 0.f, 0.f, 0.f};
            z = __builtin_amdgcn_mfma_f32_16x16x32_bf16(s_bf[ft][0][l], af[0], z, 0, 0, 0);
            const f32x4 acc =
                __builtin_amdgcn_mfma_f32_16x16x32_bf16(s_bf[ft][1][l], af[1], z, 0, 0, 0);
            const f32x4 at = s_att[ft][g4];
            const f32x4 hd = s_hd[ft][wv][l];
#pragma unroll
            for (int r = 0; r < 4; ++r) {
                float v = hs4[ft][r] + hd[r] + acc[r];
                v = v > 0.f ? v : NEG_SLOPE * v;
                ph[ft >> 1] = fmaf(v, at[r], ph[ft >> 1]);
            }
        }
        // reduce over the 4 g4-lanes sharing this edge (lanes l^16, l^32)
#pragma unroll
        for (int h = 0; h < 4; ++h) {
            ph[h] += __shfl_xor(ph[h], 16, 64);
            ph[h] += __shfl_xor(ph[h], 32, 64);
        }
        float w[4];
#pragma unroll
        for (int h = 0; h < 4; ++h) {
            w[h] = valid ? __expf(ph[h]) : 0.f;
            sw[h] += w[h];
        }
        // message accumulation: reuse hs4 registers (no second gather!)
#pragma unroll
        for (int ft = 0; ft < 8; ++ft) {
            const float wh = w[ft >> 1];
#pragma unroll
            for (int r = 0; r < 4; ++r)
                am[ft][r] = fmaf(wh, hs4[ft][r], am[ft][r]);
        }
    }

    // reduce over the 16 edge-lanes (masks 1..8 stay inside the g4 group)
#pragma unroll
    for (int m = 1; m < 16; m <<= 1) {
#pragma unroll
        for (int h = 0; h < 4; ++h) sw[h] += __shfl_xor(sw[h], m, 64);
#pragma unroll
        for (int ft = 0; ft < 8; ++ft)
#pragma unroll
            for (int r = 0; r < 4; ++r)
                am[ft][r] += __shfl_xor(am[ft][r], m, 64);
    }
    float inv[4];
#pragma unroll
    for (int h = 0; h < 4; ++h) inv[h] = 1.f / (sw[h] + 1e-16f);

    if (r16 == 0) {                     // 4 lanes store 32 features each
#pragma unroll
        for (int ft = 0; ft < 8; ++ft) {
            f32x4 o;
#pragma unroll
            for (int r = 0; r < 4; ++r) o[r] = am[ft][r] * inv[ft >> 1];
            *(f32x4*)&out[(size_t)n * F_TOT + ft * 16 + g4 * 4] = o;
        }
    }
}

extern "C" void kernel_launch(void* const* d_in, const int* in_sizes, int n_in,
                              void* d_out, int out_size, void* d_ws, size_t ws_size,
                              hipStream_t stream)
{
    const float* H   = (const float*)d_in[0];
    const int*   EI  = (const int*)d_in[1];
    const float* E   = (const float*)d_in[2];
    const float* W   = (const float*)d_in[3];
    const float* We  = (const float*)d_in[4];
    const float* att = (const float*)d_in[5];
    float* out = (float*)d_out;

    // workspace layout (~33 MB)
    float* HT        = (float*)d_ws;                          // 6.4M f32
    int2*  perm      = (int2*)(HT + (size_t)N_NODES * F_TOT); // 800k int2
    int*   deg       = (int*)(perm + N_EDGES);                // 50k
    int*   row_start = deg + N_NODES;                         // 50k+1
    int*   cursor    = row_start + N_NODES + 1;               // 50k

    hipMemsetAsync(deg, 0, N_NODES * sizeof(int), stream);

    k_hist<<<(N_EDGES + 255) / 256, 256, 0, stream>>>(EI, deg);
    k_scan<<<1, 1024, 0, stream>>>(deg, row_start, cursor);
    k_node_transform<<<512, 256, 0, stream>>>(H, W, HT);
    k_permute<<<(N_EDGES + 255) / 256, 256, 0, stream>>>(EI, cursor, perm);
    k_fused<<<(N_NODES + 3) / 4, 256, 0, stream>>>(E, We, att, HT,
                                                   perm, row_start, out);
}

// Round 4
// 661.619 us; speedup vs baseline: 1.4969x; 1.1063x over previous
//
#include <hip/hip_runtime.h>

#define N_NODES 50000
#define N_EDGES 800000
#define D_IN    128
#define D_E     64
#define NH      4
#define F_TOT   128          // NH * D_OUT
#define NEG_SLOPE 0.2f

typedef __attribute__((ext_vector_type(8))) short short8;   // 8 bf16
typedef __attribute__((ext_vector_type(4))) float f32x4;

__device__ __forceinline__ short f2bf(float x) {            // RNE f32->bf16
    unsigned u = __float_as_uint(x);
    u += 0x7FFFu + ((u >> 16) & 1u);
    return (short)(u >> 16);
}

// ---------------------------------------------------------------------------
// K1: HT[n][f] = sum_k H[n][k] * W[f][k]   (fp32, -> workspace)
// ---------------------------------------------------------------------------
__global__ __launch_bounds__(256) void k_node_transform(
    const float* __restrict__ H, const float* __restrict__ W,
    float* __restrict__ HT)
{
    __shared__ float wt[D_IN * F_TOT];   // wt[k*128+f] = W[f][k]
    const int tid = threadIdx.x;
    for (int i = tid; i < D_IN * F_TOT; i += 256) {
        const int f = i & 127, k = i >> 7;
        wt[k * F_TOT + f] = W[f * D_IN + k];
    }
    __syncthreads();

    const int l = tid & 63;
    const int w = tid >> 6;
    const int gwave  = blockIdx.x * 4 + w;
    const int nwaves = gridDim.x * 4;
    const int ngroups = N_NODES / 8;     // 6250, exact

    for (int grp = gwave; grp < ngroups; grp += nwaves) {
        const int g = grp * 8;
        float ax[8], ay[8];
#pragma unroll
        for (int j = 0; j < 8; ++j) { ax[j] = 0.f; ay[j] = 0.f; }

        for (int k4 = 0; k4 < D_IN / 4; ++k4) {
            float hv[8][4];
#pragma unroll
            for (int j = 0; j < 8; ++j)
                *(float4*)hv[j] = *(const float4*)&H[(size_t)(g + j) * D_IN + k4 * 4];
#pragma unroll
            for (int kk = 0; kk < 4; ++kk) {
                const float2 wk = *(const float2*)&wt[(k4 * 4 + kk) * F_TOT + 2 * l];
#pragma unroll
                for (int j = 0; j < 8; ++j) {
                    ax[j] = fmaf(wk.x, hv[j][kk], ax[j]);
                    ay[j] = fmaf(wk.y, hv[j][kk], ay[j]);
                }
            }
        }
#pragma unroll
        for (int j = 0; j < 8; ++j) {
            float2 r; r.x = ax[j]; r.y = ay[j];
            *(float2*)&HT[(size_t)(g + j) * F_TOT + 2 * l] = r;
        }
    }
}

// ---------------------------------------------------------------------------
// K2a: histogram of dst degrees
// ---------------------------------------------------------------------------
__global__ __launch_bounds__(256) void k_hist(
    const int* __restrict__ EI, int* __restrict__ deg)
{
    const int e = blockIdx.x * 256 + threadIdx.x;
    if (e < N_EDGES) atomicAdd(&deg[EI[N_EDGES + e]], 1);
}

// ---------------------------------------------------------------------------
// K2b: single-block exclusive scan of deg -> row_start[0..N], cursor copy
// ---------------------------------------------------------------------------
__global__ __launch_bounds__(1024) void k_scan(
    const int* __restrict__ deg, int* __restrict__ row_start,
    int* __restrict__ cursor)
{
    __shared__ int wsum[16];
    __shared__ int carry;
    const int tid = threadIdx.x;
    const int l = tid & 63;
    const int wv = tid >> 6;
    if (tid == 0) carry = 0;

    for (int base = 0; base < N_NODES; base += 1024) {
        __syncthreads();                       // [A] carry ready, wsum free
        const int cb = carry;
        const int i = base + tid;
        const int v = (i < N_NODES) ? deg[i] : 0;
        int x = v;                             // inclusive wave scan
#pragma unroll
        for (int off = 1; off < 64; off <<= 1) {
            int t = __shfl_up(x, off, 64);
            if (l >= off) x += t;
        }
        if (l == 63) wsum[wv] = x;
        __syncthreads();                       // [B] wsum ready
        int wave_off = 0;
        for (int k = 0; k < wv; ++k) wave_off += wsum[k];
        int tot = 0;
#pragma unroll
        for (int k = 0; k < 16; ++k) tot += wsum[k];
        const int excl = cb + wave_off + (x - v);
        if (i < N_NODES) { row_start[i] = excl; cursor[i] = excl; }
        __syncthreads();                       // [C] all read cb/wsum
        if (tid == 0) carry = cb + tot;
    }
    __syncthreads();
    if (tid == 0) row_start[N_NODES] = carry;
}

// ---------------------------------------------------------------------------
// K2c: CSR permutation build. perm[pos] = {eid, src}, pos from cursor atomic.
// ---------------------------------------------------------------------------
__global__ __launch_bounds__(256) void k_permute(
    const int* __restrict__ EI, int* __restrict__ cursor,
    int2* __restrict__ perm)
{
    const int e = blockIdx.x * 256 + threadIdx.x;
    if (e < N_EDGES) {
        const int src = EI[e];
        const int dst = EI[N_EDGES + e];
        const int pos = atomicAdd(&cursor[dst], 1);
        perm[pos] = make_int2(e, src);
    }
}

// ---------------------------------------------------------------------------
// K3: FUSED logits + aggregation. One wave per dst node, grid-stride.
//   R4 vs R3 (290us, occupancy 19.6%): occupancy + load-balance surgery.
//     - s_hd deduped [4][8][4] (2 KB, was 32 KB: value depends only on
//       (ft,g4), was replicated 16x across r16). LDS 48.9 -> 18.6 KB.
//       Read is same-address across each 16-lane group -> LDS broadcast.
//     - grid-stride over nodes (4096 waves ~= resident set, ~12 nodes/wave):
//       per-wave work sums ~12 Poisson(16) degrees -> variance collapses;
//       next node's loads overlap current node's epilogue (no barrier in loop).
//   Per 16-edge CSR tile (lane-per-edge layout, operand-swapped MFMA):
//     D(16f x 16e) = We_tile(16f x 32k) @ E_tile^T(32k x 16e)
//     D: col=lane&15 -> EDGE (CSR slot), row=(lane>>4)*4+reg -> feature
// ---------------------------------------------------------------------------
__global__ __launch_bounds__(256, 2) void k_fused(
    const float* __restrict__ E, const float* __restrict__ We,
    const float* __restrict__ att, const float* __restrict__ HT,
    const int2* __restrict__ perm, const int* __restrict__ row_start,
    float* __restrict__ out)
{
    __shared__ short8 s_bf[8][2][64];   // 16 KB: per-lane We fragments (bf16)
    __shared__ f32x4  s_att[8][4];      // 512 B
    __shared__ f32x4  s_hd[4][8][4];    // 2 KB: dst-row fragments, per wave

    const int tid = threadIdx.x;
    const int l   = tid & 63;
    const int wv  = tid >> 6;
    const int r16 = l & 15;          // edge slot within tile
    const int g4  = l >> 4;          // feature group / k-chunk selector

    if (wv == 0) {
#pragma unroll
        for (int ft = 0; ft < 8; ++ft) {
#pragma unroll
            for (int kc = 0; kc < 2; ++kc) {
                const float* wp = &We[(size_t)(ft * 16 + r16) * D_E + kc * 32 + g4 * 8];
                const f32x4 lo = *(const f32x4*)wp;
                const f32x4 hi = *(const f32x4*)(wp + 4);
                short8 b;
                b[0] = f2bf(lo[0]); b[1] = f2bf(lo[1]); b[2] = f2bf(lo[2]); b[3] = f2bf(lo[3]);
                b[4] = f2bf(hi[0]); b[5] = f2bf(hi[1]); b[6] = f2bf(hi[2]); b[7] = f2bf(hi[3]);
                s_bf[ft][kc][l] = b;
            }
        }
        if (l < 32) {
            const int ft = l >> 2, g = l & 3;
            s_att[ft][g] = *(const f32x4*)&att[ft * 16 + g * 4];
        }
    }
    __syncthreads();

    const int gw      = blockIdx.x * 4 + wv;
    const int gstride = gridDim.x * 4;

    for (int n = gw; n < N_NODES; n += gstride) {
        const int beg = row_start[n];
        const int end = row_start[n + 1];

        // dst row -> LDS (512 B/wave): 32 lanes, one coalesced dwordx4 each.
        // Same-wave produce/consume; lgkmcnt ordering, no barrier needed.
        if (l < 32)
            s_hd[wv][l >> 2][l & 3] = *(const f32x4*)&HT[(size_t)n * F_TOT + l * 4];

        f32x4 am[8];                    // per-lane message accum (this edge)
#pragma unroll
        for (int ft = 0; ft < 8; ++ft) am[ft] = (f32x4){0.f, 0.f, 0.f, 0.f};
        float sw[4] = {0.f, 0.f, 0.f, 0.f};

        for (int t = beg; t < end; t += 16) {
            const int  idx   = t + r16;
            const bool valid = idx < end;
            const int2 pe    = perm[valid ? idx : end - 1];
            const int  eid   = pe.x;
            const int  sr    = pe.y;

            // HT[src] gather: 8 independent dwordx4 (logit AND message)
            const float* hsp = &HT[(size_t)sr * F_TOT + g4 * 4];
            f32x4 hs4[8];
#pragma unroll
            for (int ft = 0; ft < 8; ++ft)
                hs4[ft] = *(const f32x4*)(hsp + ft * 16);

            // E row -> bf16 B-fragments
            short8 af[2];
#pragma unroll
            for (int kc = 0; kc < 2; ++kc) {
                const float* ep = &E[(size_t)eid * D_E + kc * 32 + g4 * 8];
                const f32x4 lo = *(const f32x4*)ep;
                const f32x4 hi = *(const f32x4*)(ep + 4);
                short8 a;
                a[0] = f2bf(lo[0]); a[1] = f2bf(lo[1]); a[2] = f2bf(lo[2]); a[3] = f2bf(lo[3]);
                a[4] = f2bf(hi[0]); a[5] = f2bf(hi[1]); a[6] = f2bf(hi[2]); a[7] = f2bf(hi[3]);
                af[kc] = a;
            }

            float ph[4] = {0.f, 0.f, 0.f, 0.f};
#pragma unroll
            for (int ft = 0; ft < 8; ++ft) {
                f32x4 z = {0.f, 0.f, 0.f, 0.f};
                z = __builtin_amdgcn_mfma_f32_16x16x32_bf16(s_bf[ft][0][l], af[0], z, 0, 0, 0);
                const f32x4 acc =
                    __builtin_amdgcn_mfma_f32_16x16x32_bf16(s_bf[ft][1][l], af[1], z, 0, 0, 0);
                const f32x4 at = s_att[ft][g4];
                const f32x4 hd = s_hd[wv][ft][g4];   // LDS broadcast read
#pragma unroll
                for (int r = 0; r < 4; ++r) {
                    float v = hs4[ft][r] + hd[r] + acc[r];
                    v = v > 0.f ? v : NEG_SLOPE * v;
                    ph[ft >> 1] = fmaf(v, at[r], ph[ft >> 1]);
                }
            }
            // reduce over the 4 g4-lanes sharing this edge (l^16, l^32)
#pragma unroll
            for (int h = 0; h < 4; ++h) {
                ph[h] += __shfl_xor(ph[h], 16, 64);
                ph[h] += __shfl_xor(ph[h], 32, 64);
            }
            float w[4];
#pragma unroll
            for (int h = 0; h < 4; ++h) {
                w[h] = valid ? __expf(ph[h]) : 0.f;
                sw[h] += w[h];
            }
            // message accumulation: reuse hs4 registers (no second gather!)
#pragma unroll
            for (int ft = 0; ft < 8; ++ft) {
                const float wh = w[ft >> 1];
#pragma unroll
                for (int r = 0; r < 4; ++r)
                    am[ft][r] = fmaf(wh, hs4[ft][r], am[ft][r]);
            }
        }

        // reduce over the 16 edge-lanes (masks 1..8 stay inside g4 group)
#pragma unroll
        for (int m = 1; m < 16; m <<= 1) {
#pragma unroll
            for (int h = 0; h < 4; ++h) sw[h] += __shfl_xor(sw[h], m, 64);
#pragma unroll
            for (int ft = 0; ft < 8; ++ft)
#pragma unroll
                for (int r = 0; r < 4; ++r)
                    am[ft][r] += __shfl_xor(am[ft][r], m, 64);
        }
        float inv[4];
#pragma unroll
        for (int h = 0; h < 4; ++h) inv[h] = 1.f / (sw[h] + 1e-16f);

        if (r16 == 0) {                 // 4 lanes store 32 features each
#pragma unroll
            for (int ft = 0; ft < 8; ++ft) {
                f32x4 o;
#pragma unroll
                for (int r = 0; r < 4; ++r) o[r] = am[ft][r] * inv[ft >> 1];
                *(f32x4*)&out[(size_t)n * F_TOT + ft * 16 + g4 * 4] = o;
            }
        }
    }
}

extern "C" void kernel_launch(void* const* d_in, const int* in_sizes, int n_in,
                              void* d_out, int out_size, void* d_ws, size_t ws_size,
                              hipStream_t stream)
{
    const float* H   = (const float*)d_in[0];
    const int*   EI  = (const int*)d_in[1];
    const float* E   = (const float*)d_in[2];
    const float* W   = (const float*)d_in[3];
    const float* We  = (const float*)d_in[4];
    const float* att = (const float*)d_in[5];
    float* out = (float*)d_out;

    // workspace layout (~33 MB)
    float* HT        = (float*)d_ws;                          // 6.4M f32
    int2*  perm      = (int2*)(HT + (size_t)N_NODES * F_TOT); // 800k int2
    int*   deg       = (int*)(perm + N_EDGES);                // 50k
    int*   row_start = deg + N_NODES;                         // 50k+1
    int*   cursor    = row_start + N_NODES + 1;               // 50k

    hipMemsetAsync(deg, 0, N_NODES * sizeof(int), stream);

    k_hist<<<(N_EDGES + 255) / 256, 256, 0, stream>>>(EI, deg);
    k_scan<<<1, 1024, 0, stream>>>(deg, row_start, cursor);
    k_node_transform<<<512, 256, 0, stream>>>(H, W, HT);
    k_permute<<<(N_EDGES + 255) / 256, 256, 0, stream>>>(EI, cursor, perm);
    k_fused<<<1024, 256, 0, stream>>>(E, We, att, HT, perm, row_start, out);
}